// Round 1
// baseline (75.109 us; speedup 1.0000x reference)
//
#include <hip/hip_runtime.h>

// NFP pooling: out[b,o,i,j] = -sum_c |x[b,c,i+1,j+1] - x[b,c,i+di,j+dj]|
// for the 8 non-center (di,dj) in a 3x3 window. x: (8,128,224,224) f32.
// out: (8,8,222,222) f32.

constexpr int B  = 8;
constexpr int C  = 128;
constexpr int H  = 224;
constexpr int W  = 224;
constexpr int HO = 222;
constexpr int WO = 222;
constexpr int TPR = WO / 2;                 // 111 column-pairs per output row
constexpr int PLANE = H * W;                // 50176 floats per channel plane
constexpr int OPLANE = HO * WO;             // 49284 floats per output plane
constexpr int TOTAL = B * HO * TPR;         // 197,136 threads

__global__ __launch_bounds__(256)
void nfp_sad_kernel(const float* __restrict__ x, float* __restrict__ out) {
    int id = blockIdx.x * 256 + threadIdx.x;
    if (id >= TOTAL) return;

    int t = id % TPR;           // column-pair index: output cols 2t, 2t+1
    int r = id / TPR;
    int i = r % HO;             // output row
    int b = r / HO;             // batch

    // input rows i..i+2, cols 2t..2t+3 (all <= 223, in-bounds; 8B aligned)
    const float* p0 = x + (size_t)b * C * PLANE + (size_t)i * W + 2 * t;

    float acc[2][8];
#pragma unroll
    for (int q = 0; q < 2; ++q)
#pragma unroll
        for (int o = 0; o < 8; ++o) acc[q][o] = 0.0f;

#pragma unroll 4
    for (int c = 0; c < C; ++c) {
        const float* p = p0 + (size_t)c * PLANE;
        float2 a0 = *reinterpret_cast<const float2*>(p);
        float2 a1 = *reinterpret_cast<const float2*>(p + 2);
        float2 b0 = *reinterpret_cast<const float2*>(p + W);
        float2 b1 = *reinterpret_cast<const float2*>(p + W + 2);
        float2 c0 = *reinterpret_cast<const float2*>(p + 2 * W);
        float2 c1 = *reinterpret_cast<const float2*>(p + 2 * W + 2);

        float r0[4] = {a0.x, a0.y, a1.x, a1.y};
        float r1[4] = {b0.x, b0.y, b1.x, b1.y};
        float r2[4] = {c0.x, c0.y, c1.x, c1.y};

#pragma unroll
        for (int q = 0; q < 2; ++q) {
            float ctr = r1[q + 1];
            // offset order: (0,0),(0,1),(0,2),(1,0),(1,2),(2,0),(2,1),(2,2)
            acc[q][0] += __builtin_fabsf(ctr - r0[q + 0]);
            acc[q][1] += __builtin_fabsf(ctr - r0[q + 1]);
            acc[q][2] += __builtin_fabsf(ctr - r0[q + 2]);
            acc[q][3] += __builtin_fabsf(ctr - r1[q + 0]);
            acc[q][4] += __builtin_fabsf(ctr - r1[q + 2]);
            acc[q][5] += __builtin_fabsf(ctr - r2[q + 0]);
            acc[q][6] += __builtin_fabsf(ctr - r2[q + 1]);
            acc[q][7] += __builtin_fabsf(ctr - r2[q + 2]);
        }
    }

    float* op = out + (size_t)b * 8 * OPLANE + (size_t)i * WO + 2 * t;
#pragma unroll
    for (int o = 0; o < 8; ++o) {
        float2 v = make_float2(-acc[0][o], -acc[1][o]);
        *reinterpret_cast<float2*>(op + (size_t)o * OPLANE) = v;
    }
}

extern "C" void kernel_launch(void* const* d_in, const int* in_sizes, int n_in,
                              void* d_out, int out_size, void* d_ws, size_t ws_size,
                              hipStream_t stream) {
    const float* x = (const float*)d_in[0];
    float* out = (float*)d_out;
    int blocks = (TOTAL + 255) / 256;
    nfp_sad_kernel<<<blocks, 256, 0, stream>>>(x, out);
}